// Round 12
// baseline (1157.344 us; speedup 1.0000x reference)
//
#include <hip/hip_runtime.h>
#include <stdint.h>

typedef __bf16 bf16;
typedef bf16 bf16x8 __attribute__((ext_vector_type(8)));
typedef float f32x4 __attribute__((ext_vector_type(4)));
typedef int int4v __attribute__((ext_vector_type(4)));
typedef uint32_t u32;

#define DEV static __device__ __forceinline__
// Relaxed barrier (m201 recipe): plain s_barrier builtin, NO memory clobber.
// Pure ds_read/MFMA may be compiler-scheduled across it; side-effecting
// global_load_lds stays ordered vs other side-effecting ops. The true memory
// fences in gemm256 are the two vmcnt asm statements (memory-clobbered).
#define SBAR() __builtin_amdgcn_s_barrier()

DEV void g2l16(const void* g, void* l) {
  __builtin_amdgcn_global_load_lds((__attribute__((address_space(1))) void*)g,
                                   (__attribute__((address_space(3))) void*)l, 16, 0, 0);
}

DEV u32 pkbf16(float a, float b) {
  union { bf16 h[2]; u32 w; } u;
  u.h[0] = (bf16)a; u.h[1] = (bf16)b;
  return u.w;
}

DEV float fexp2(float x) { return __builtin_amdgcn_exp2f(x); }

// ---------------------------------------------------------------- cvt f32->bf16
__global__ void cvt_bf16(const float* __restrict__ in, bf16* __restrict__ out, int n8) {
  const int i = blockIdx.x * 256 + threadIdx.x;
  if (i >= n8) return;
  const f32x4* p = (const f32x4*)in + (size_t)i * 2;
  const f32x4 a = p[0], b = p[1];
  bf16x8 o;
  o[0]=(bf16)a[0]; o[1]=(bf16)a[1]; o[2]=(bf16)a[2]; o[3]=(bf16)a[3];
  o[4]=(bf16)b[0]; o[5]=(bf16)b[1]; o[6]=(bf16)b[2]; o[7]=(bf16)b[3];
  ((bf16x8*)out)[i] = o;
}

// ---------------------------------------------------------------- MFMA quadrant helper
template<int MO, int NO>
DEV void mmaq(f32x4 (&acc)[8][4], const bf16x8 (&af)[4][2], const bf16x8 (&bf)[2][2]) {
#pragma unroll
  for (int m2 = 0; m2 < 4; ++m2)
#pragma unroll
    for (int n2 = 0; n2 < 2; ++n2)
#pragma unroll
      for (int kk = 0; kk < 2; ++kk)
        acc[MO + m2][NO + n2] = __builtin_amdgcn_mfma_f32_16x16x32_bf16(
            af[m2][kk], bf[n2][kk], acc[MO + m2][NO + n2], 0, 0, 0);
}

// ---------------------------------------------------------------- GEMM 256x256, 8-phase
// Round-12: barriers relaxed to __builtin_amdgcn_s_barrier() (no memory
// clobber) per the m201 recipe. The two vmcnt asm fences at P0/P4 carry the
// memory-ordering load: buf reads can't hoist above the vmcnt that drains
// their fill; g2l16 stages are side-effecting and stay ordered vs barriers.
template<int OUT_BF16>
__global__ __launch_bounds__(512, 2)
void gemm256(const bf16* __restrict__ A, const bf16* __restrict__ Bt,
             void* __restrict__ Cout, const float* __restrict__ bias,
             int M, int N, int K) {
  __shared__ __align__(16) char L[131072];
  const int tid = threadIdx.x, lane = tid & 63, wid = tid >> 6;
  const int wm = wid >> 2, wn = wid & 3;
  const int q = lane & 15, g = lane >> 4;
  const int mt = M >> 8;
  const int nwg = gridDim.x, bid = blockIdx.x;
  const int wg = (bid & 7) * (nwg >> 3) + (bid >> 3);   // XCD swizzle (nwg%8==0)
  const int bm = wg % mt, bn = wg / mt;
  const size_t Kb = (size_t)K * 2;
  const char* Ab = (const char*)A + (size_t)bm * 256 * Kb;
  const char* Bb = (const char*)Bt + (size_t)bn * 256 * Kb;
  const int NT = K >> 6;

  const int csw0 = (g ^ (q & 7)) << 4;
  const int csw1 = ((4 + g) ^ (q & 7)) << 4;
  const int baseA0 = wm * 16384 + q * 128;
  const int baseA1 = 65536 + baseA0;
  const int bBq = 32768 + (wn >> 1) * 16384 + (wn & 1) * 8192 + q * 128;
  const int baseB0 = bBq, baseB1 = 65536 + bBq;

#define RD_A(AF, BASE) do { _Pragma("unroll") \
  for (int m2_ = 0; m2_ < 4; ++m2_) { \
    (AF)[m2_][0] = *(const bf16x8*)(L + (BASE) + m2_ * 2048 + csw0); \
    (AF)[m2_][1] = *(const bf16x8*)(L + (BASE) + m2_ * 2048 + csw1); } } while (0)
#define RD_B(BF, BASE) do { _Pragma("unroll") \
  for (int n2_ = 0; n2_ < 2; ++n2_) { \
    (BF)[n2_][0] = *(const bf16x8*)(L + (BASE) + n2_ * 2048 + csw0); \
    (BF)[n2_][1] = *(const bf16x8*)(L + (BASE) + n2_ * 2048 + csw1); } } while (0)

  auto stage = [&](const char* gb, int ldsHalfBase, int halfRow, int tt) {
#pragma unroll
    for (int r2 = 0; r2 < 2; ++r2) {
      const int rel = r2 * 8192 + wid * 1024;
      const int o = rel + (lane << 4);
      const int row = o >> 7;
      const int kbyte = (o & 127) ^ ((row & 7) << 4);
      g2l16(gb + (size_t)(halfRow * 128 + row) * Kb + (size_t)(tt * 128 + kbyte),
            L + ldsHalfBase + rel);
    }
  };

  f32x4 acc[8][4];
  const f32x4 zero = {0.f, 0.f, 0.f, 0.f};
#pragma unroll
  for (int m = 0; m < 8; ++m)
#pragma unroll
    for (int n = 0; n < 4; ++n) acc[m][n] = zero;
  bf16x8 af[4][2], bflo[2][2], bfhi[2][2];

  stage(Bb, 32768, 0, 0);          stage(Bb, 32768 + 16384, 1, 0);
  stage(Ab, 0, 0, 0);              stage(Ab, 16384, 1, 0);
  stage(Bb, 65536 + 32768, 0, 1);  stage(Bb, 65536 + 32768 + 16384, 1, 1);

  for (int t = 0; t < NT; t += 2) {
    const int tc1 = t + 1;
    const int tc2 = (t + 2 < NT) ? t + 2 : NT - 1;
    const int tc3 = (t + 3 < NT) ? t + 3 : NT - 1;
    // ---- P0: tile t, m0-3 x n0-1 (all B-frags + A-low read here)
    asm volatile("s_waitcnt vmcnt(4)" ::: "memory");
    SBAR();
    RD_A(af, baseA0);
    RD_B(bflo, baseB0);
    RD_B(bfhi, baseB0 + 4096);
    stage(Ab, 65536, 0, tc1);
    SBAR();
    __builtin_amdgcn_s_setprio(1);
    mmaq<0, 0>(acc, af, bflo);
    __builtin_amdgcn_s_setprio(0);
    SBAR();
    // ---- P1: m0-3 x n2-3 (pure MFMA)
    stage(Ab, 65536 + 16384, 1, tc1);
    SBAR();
    __builtin_amdgcn_s_setprio(1);
    mmaq<0, 2>(acc, af, bfhi);
    __builtin_amdgcn_s_setprio(0);
    SBAR();
    // ---- P2: m4-7 x n0-1
    RD_A(af, baseA0 + 8192);
    stage(Bb, 32768, 0, tc2);
    SBAR();
    __builtin_amdgcn_s_setprio(1);
    mmaq<4, 0>(acc, af, bflo);
    __builtin_amdgcn_s_setprio(0);
    SBAR();
    // ---- P3: m4-7 x n2-3 (pure MFMA)
    stage(Bb, 32768 + 16384, 1, tc2);
    SBAR();
    __builtin_amdgcn_s_setprio(1);
    mmaq<4, 2>(acc, af, bfhi);
    __builtin_amdgcn_s_setprio(0);
    SBAR();
    // ---- P4: tile t+1, m0-3 x n0-1
    asm volatile("s_waitcnt vmcnt(4)" ::: "memory");
    SBAR();
    RD_A(af, baseA1);
    RD_B(bflo, baseB1);
    RD_B(bfhi, baseB1 + 4096);
    stage(Ab, 0, 0, tc2);
    SBAR();
    __builtin_amdgcn_s_setprio(1);
    mmaq<0, 0>(acc, af, bflo);
    __builtin_amdgcn_s_setprio(0);
    SBAR();
    // ---- P5: pure MFMA
    stage(Ab, 16384, 1, tc2);
    SBAR();
    __builtin_amdgcn_s_setprio(1);
    mmaq<0, 2>(acc, af, bfhi);
    __builtin_amdgcn_s_setprio(0);
    SBAR();
    // ---- P6
    RD_A(af, baseA1 + 8192);
    stage(Bb, 65536 + 32768, 0, tc3);
    SBAR();
    __builtin_amdgcn_s_setprio(1);
    mmaq<4, 0>(acc, af, bflo);
    __builtin_amdgcn_s_setprio(0);
    SBAR();
    // ---- P7: pure MFMA
    stage(Bb, 65536 + 32768 + 16384, 1, tc3);
    SBAR();
    __builtin_amdgcn_s_setprio(1);
    mmaq<4, 2>(acc, af, bfhi);
    __builtin_amdgcn_s_setprio(0);
    SBAR();
  }
  asm volatile("s_waitcnt vmcnt(0)" ::: "memory");

  const int row0 = bm * 256 + wm * 128 + g * 4;
  const int col0 = bn * 256 + wn * 64 + q;
#pragma unroll
  for (int n = 0; n < 4; ++n) {
    const int col = col0 + n * 16;
    const float bv = bias[col];
#pragma unroll
    for (int m = 0; m < 8; ++m) {
#pragma unroll
      for (int r = 0; r < 4; ++r) {
        const int row = row0 + m * 16 + r;
        const float v = acc[m][n][r] + bv;
        if (OUT_BF16) ((bf16*)Cout)[(size_t)row * N + col] = (bf16)v;
        else          ((float*)Cout)[(size_t)row * N + col] = v;
      }
    }
  }
#undef RD_A
#undef RD_B
}

// ---------------------------------------------------------------- GEMM 128x128 (small N)
template<int OUT_BF16>
__global__ __launch_bounds__(256, 2)
void gemm_bt(const bf16* __restrict__ A, const bf16* __restrict__ Bt,
             void* __restrict__ Cout, const float* __restrict__ bias,
             int M, int N, int K) {
  __shared__ __align__(16) char As[16384];
  __shared__ __align__(16) char Bs[16384];
  const int tid  = threadIdx.x;
  const int lane = tid & 63;
  const int wid  = tid >> 6;
  const int mt = M >> 7;
  const int nwg = gridDim.x;
  const int bid = blockIdx.x;
  const int wg = (bid & 7) * (nwg >> 3) + (bid >> 3);
  const int bm = wg % mt;
  const int bn = wg / mt;

  const size_t Kb = (size_t)K * 2;
  const char* Ab = (const char*)A + (size_t)bm * 128 * Kb;
  const char* Bb = (const char*)Bt + (size_t)bn * 128 * Kb;

  const int wr = wid >> 1, wc = wid & 1;
  const int q = lane & 15, g = lane >> 4;

  const f32x4 zero = {0.f, 0.f, 0.f, 0.f};
  f32x4 acc[4][4];
#pragma unroll
  for (int m = 0; m < 4; ++m)
#pragma unroll
    for (int n = 0; n < 4; ++n) acc[m][n] = zero;

  for (int k0 = 0; k0 < K; k0 += 64) {
    __syncthreads();
#pragma unroll
    for (int it = 0; it < 4; ++it) {
      const int obase = (it * 4 + wid) << 10;
      const int o = obase + (lane << 4);
      const int row = o >> 7;
      const int kbyte = (o & 127) ^ ((row & 7) << 4);
      g2l16(Ab + (size_t)row * Kb + (size_t)(k0 * 2 + kbyte), As + obase);
      g2l16(Bb + (size_t)row * Kb + (size_t)(k0 * 2 + kbyte), Bs + obase);
    }
    __syncthreads();
#pragma unroll
    for (int kk = 0; kk < 2; ++kk) {
      bf16x8 af[4], bfv[4];
#pragma unroll
      for (int m = 0; m < 4; ++m) {
        const int r = wr * 64 + m * 16 + q;
        const int byte = (r * 128 + kk * 64 + g * 16) ^ ((r & 7) << 4);
        af[m] = *(const bf16x8*)(As + byte);
      }
#pragma unroll
      for (int n = 0; n < 4; ++n) {
        const int r = wc * 64 + n * 16 + q;
        const int byte = (r * 128 + kk * 64 + g * 16) ^ ((r & 7) << 4);
        bfv[n] = *(const bf16x8*)(Bs + byte);
      }
#pragma unroll
      for (int m = 0; m < 4; ++m)
#pragma unroll
        for (int n = 0; n < 4; ++n)
          acc[m][n] = __builtin_amdgcn_mfma_f32_16x16x32_bf16(af[m], bfv[n], acc[m][n], 0, 0, 0);
    }
  }

  const int col0 = bn * 128 + wc * 64 + q;
  const int row0 = bm * 128 + wr * 64 + g * 4;
#pragma unroll
  for (int n = 0; n < 4; ++n) {
    const int col = col0 + n * 16;
    const float bv = bias[col];
#pragma unroll
    for (int m = 0; m < 4; ++m) {
#pragma unroll
      for (int r = 0; r < 4; ++r) {
        const int row = row0 + m * 16 + r;
        const float v = acc[m][n][r] + bv;
        if (OUT_BF16) ((bf16*)Cout)[(size_t)row * N + col] = (bf16)v;
        else          ((float*)Cout)[(size_t)row * N + col] = v;
      }
    }
  }
}

// ---------------------------------------------------------------- V transpose per head
__global__ void transpose_v(const bf16* __restrict__ vlin, bf16* __restrict__ vt) {
  __shared__ __align__(16) bf16 t[64][80];
  const int tid = threadIdx.x;
  const int bh = blockIdx.z;
  const int jt = blockIdx.x, dt = blockIdx.y;
  const bf16* src = vlin + (size_t)bh * 1048576 + (size_t)(jt * 64) * 512 + dt * 64;
  bf16* dst = vt + (size_t)bh * 1048576 + (size_t)(dt * 64) * 2048 + jt * 64;
#pragma unroll
  for (int it = 0; it < 2; ++it) {
    const int c = it * 256 + tid;
    const int r = c >> 3, c8 = (c & 7) * 8;
    *(int4v*)&t[r][c8] = *(const int4v*)(src + (size_t)r * 512 + c8);
  }
  __syncthreads();
#pragma unroll
  for (int it = 0; it < 2; ++it) {
    const int c = it * 256 + tid;
    const int d = c >> 3, j8 = (c & 7) * 8;
    bf16x8 v;
#pragma unroll
    for (int jj = 0; jj < 8; ++jj) v[jj] = t[j8 + jj][d];
    *(bf16x8*)(dst + (size_t)d * 2048 + j8) = v;
  }
}

// ---------------------------------------------------------------- flash attention
// Q: [b][hq][2048][128], K: [b][h][2048][128], VT: [b][h][512][2048], O: [b][hq][2048][512]
// Spill-free dbuf via __syncthreads (VGPR 108 + 128 acc = 236 regs -> 1 block/CU,
// 2 waves/SIMD; register-bound). Global LPT dispatch: 1D grid, qt = 15 - (bid>>6).
// KEEP __syncthreads here: raw-asm sync variants spilled ~1GB scratch (rounds 6-8).
__global__ __launch_bounds__(512, 2)
void attn(const bf16* __restrict__ Q, const bf16* __restrict__ Kl,
          const bf16* __restrict__ VT, bf16* __restrict__ O) {
  constexpr float SC = 0.08838834764831845f * 1.4426950408889634f; // 1/sqrt(128)*log2(e)
  __shared__ __align__(16) char L[81920];   // buf bb in {0,40960}: K 8KB | V 32KB
  const int tid = threadIdx.x, lane = tid & 63, wid = tid >> 6;
  const int bid = blockIdx.x;
  const int qt = 15 - (bid >> 6);           // global LPT: longest first
  const int hq = (bid >> 1) & 31;
  const int b  = bid & 1;
  const int h = hq & 7;
  const char* qb = (const char*)(Q + (((size_t)b * 32 + hq) << 18));
  const char* kb = (const char*)(Kl + (((size_t)b * 8 + h) << 18));
  const char* vb = (const char*)(VT + (((size_t)b * 8 + h) << 20));
  bf16* ob = (bf16*)(O + (((size_t)b * 32 + hq) << 20));

  const int g = lane >> 4, q = lane & 15;
  const int qrow = qt * 128 + wid * 16 + q;
  const float NEGINF = -__builtin_inff();

  auto stageKV = [&](int j0, int bbase) {
    {   // K tile [32][128], XOR swizzled
      const int obase = wid << 10;
      const int o = obase + (lane << 4);
      const int row = o >> 8;
      const int cb = (o & 255) ^ ((row & 7) << 4);
      g2l16(kb + (size_t)(j0 + row) * 256 + cb, L + bbase + obase);
    }
#pragma unroll
    for (int it = 0; it < 4; ++it) {   // V tile [512][32], granule-permuted
      const int obase = (it * 8 + wid) << 10;
      const int o = obase + (lane << 4);
      const int sl = o >> 4;
      const int dpair = sl >> 3;
      const int w2 = (sl & 7) ^ (dpair & 7);
      const int d = dpair * 2 + (w2 >> 2);
      const int jo = w2 & 3;
      g2l16(vb + (size_t)d * 4096 + (size_t)(j0 + jo * 8) * 2,
            L + bbase + 8192 + obase);
    }
  };

  bf16x8 qf[4];
#pragma unroll
  for (int kk = 0; kk < 4; ++kk)
    qf[kk] = *(const bf16x8*)(qb + (size_t)qrow * 256 + kk * 64 + g * 16);

  const f32x4 zero = {0.f, 0.f, 0.f, 0.f};
  f32x4 acc[32];
#pragma unroll
  for (int i = 0; i < 32; ++i) acc[i] = zero;
  float mrun = NEGINF, lrun = 0.f;

  const int ntiles = qt * 4 + 4;
  const int jmax = (ntiles - 1) * 32;
  stageKV(0, 0);
  __syncthreads();          // drain tile 0
  int bb = 0;

#pragma unroll 1
  for (int jt = 0; jt < ntiles; ++jt) {
    const int j0 = jt * 32;
    const int jn = (j0 < jmax) ? j0 + 32 : jmax;   // clamp: harmless re-stage at end
    stageKV(jn, bb ^ 40960);   // in flight during this tile's compute
    const char* KsB = L + bb;
    const char* VsB = L + bb + 8192;

    // S^T = K * Q^T  (D: col = q, row = j = 4*g + r [+16])
    f32x4 s0 = zero, s1 = zero;
    __builtin_amdgcn_s_setprio(1);
#pragma unroll
    for (int kk = 0; kk < 4; ++kk) {
      {
        const int r = q;
        const int byte = (r * 256 + kk * 64 + g * 16) ^ ((r & 7) << 4);
        const bf16x8 kf = *(const bf16x8*)(KsB + byte);
        s0 = __builtin_amdgcn_mfma_f32_16x16x32_bf16(kf, qf[kk], s0, 0, 0, 0);
      }
      {
        const int r = 16 + q;
        const int byte = (r * 256 + kk * 64 + g * 16) ^ ((r & 7) << 4);
        const bf16x8 kf = *(const bf16x8*)(KsB + byte);
        s1 = __builtin_amdgcn_mfma_f32_16x16x32_bf16(kf, qf[kk], s1, 0, 0, 0);
      }
    }
    __builtin_amdgcn_s_setprio(0);

    float sv[8];
#pragma unroll
    for (int r = 0; r < 4; ++r) {
      float v0 = s0[r] * SC;
      float v1 = s1[r] * SC;
      if (j0 + g * 4 + r > qrow)      v0 = NEGINF;
      if (j0 + 16 + g * 4 + r > qrow) v1 = NEGINF;
      sv[r] = v0; sv[4 + r] = v1;
    }
    float pmax = fmaxf(fmaxf(fmaxf(sv[0], sv[1]), fmaxf(sv[2], sv[3])),
                       fmaxf(fmaxf(sv[4], sv[5]), fmaxf(sv[6], sv[7])));
    pmax = fmaxf(pmax, __shfl_xor(pmax, 16));
    pmax = fmaxf(pmax, __shfl_xor(pmax, 32));

    if (!__all(pmax <= mrun + 11.5f)) {     // defer-max rescale
      const float mnew = fmaxf(mrun, pmax);
      const float cf = fexp2(mrun - mnew);
      float cfr[4];
#pragma unroll
      for (int r = 0; r < 4; ++r) cfr[r] = __shfl(cf, g * 4 + r);
#pragma unroll
      for (int i = 0; i < 32; ++i) {
        acc[i][0] *= cfr[0]; acc[i][1] *= cfr[1];
        acc[i][2] *= cfr[2]; acc[i][3] *= cfr[3];
      }
      lrun *= cf;
      mrun = mnew;
    }

    u32 u0[2], u1[2];
    {
      const float p0 = fexp2(sv[0] - mrun), p1 = fexp2(sv[1] - mrun);
      const float p2 = fexp2(sv[2] - mrun), p3 = fexp2(sv[3] - mrun);
      const float p4 = fexp2(sv[4] - mrun), p5 = fexp2(sv[5] - mrun);
      const float p6 = fexp2(sv[6] - mrun), p7 = fexp2(sv[7] - mrun);
      lrun += ((p0 + p1) + (p2 + p3)) + ((p4 + p5) + (p6 + p7));
      u0[0] = pkbf16(p0, p1); u0[1] = pkbf16(p2, p3);
      u1[0] = pkbf16(p4, p5); u1[1] = pkbf16(p6, p7);
    }

    // Redistribute P^T into MFMA A-layout: lane needs j = 8g+2i, 8g+2i+1
    u32 aw[4];
#pragma unroll
    for (int i = 0; i < 4; ++i) {
      const int src = ((2 * g + (i >> 1)) & 3) * 16 + q;
      const u32 v0 = (u32)__shfl((int)u0[i & 1], src);
      const u32 v1 = (u32)__shfl((int)u1[i & 1], src);
      aw[i] = (g < 2) ? v0 : v1;
    }
    union { u32 w[4]; bf16x8 v; } pu;
    pu.w[0] = aw[0]; pu.w[1] = aw[1]; pu.w[2] = aw[2]; pu.w[3] = aw[3];
    const bf16x8 pa = pu.v;

    __builtin_amdgcn_s_setprio(1);
#pragma unroll
    for (int nd = 0; nd < 32; ++nd) {
      const int d = nd * 16 + q;
      const int w2 = ((d & 1) * 4 + g) ^ ((d >> 1) & 7);
      const int byte = (d >> 1) * 128 + w2 * 16;
      const bf16x8 vf = *(const bf16x8*)(VsB + byte);
      acc[nd] = __builtin_amdgcn_mfma_f32_16x16x32_bf16(pa, vf, acc[nd], 0, 0, 0);
    }
    __builtin_amdgcn_s_setprio(0);
    __syncthreads();   // drains next-tile stage (overlapped with compute above)
    bb ^= 40960;       // and fences all reads of buf bb before it is overwritten
  }

  float lt = lrun + __shfl_xor(lrun, 16);
  lt += __shfl_xor(lt, 32);
  const float linv = 1.f / lt;
  float lr[4];
#pragma unroll
  for (int r = 0; r < 4; ++r) lr[r] = __shfl(linv, g * 4 + r);
#pragma unroll
  for (int nd = 0; nd < 32; ++nd) {
#pragma unroll
    for (int r = 0; r < 4; ++r) {
      const int qq = qt * 128 + wid * 16 + g * 4 + r;
      ob[(size_t)qq * 512 + nd * 16 + q] = (bf16)(acc[nd][r] * lr[r]);
    }
  }
}

// ---------------------------------------------------------------- launch
extern "C" void kernel_launch(void* const* d_in, const int* in_sizes, int n_in,
                              void* d_out, int out_size, void* d_ws, size_t ws_size,
                              hipStream_t stream) {
  (void)in_sizes; (void)n_in; (void)out_size; (void)ws_size;
  const float* x   = (const float*)d_in[0];
  const float* WQw = (const float*)d_in[2];
  const float* WQb = (const float*)d_in[3];
  const float* WKw = (const float*)d_in[4];
  const float* WKb = (const float*)d_in[5];
  const float* WVw = (const float*)d_in[6];
  const float* WVb = (const float*)d_in[7];
  const float* W0w = (const float*)d_in[8];
  const float* W0b = (const float*)d_in[9];
  float* out = (float*)d_out;

  bf16* ws = (bf16*)d_ws;
  size_t off = 0;
  auto alloc = [&](size_t n) { bf16* p = ws + off; off += n; return p; };
  bf16* xb   = alloc(16777216);   // x bf16           (2,2048,4096)
  bf16* wqb  = alloc(16777216);   // WQ bf16          (4096,4096)
  bf16* wkb  = alloc(4194304);    // WK bf16          (1024,4096)
  bf16* wvb  = alloc(16777216);   // WV bf16          (4096,4096)
  bf16* w0b  = alloc(67108864);   // W0 bf16          (4096,16384)
  bf16* qlin = alloc(16777216);   // Q                (2,2048,4096)
  bf16* klin = alloc(4194304);    // K                (2,2048,1024)
  bf16* vlin = alloc(16777216);   // V                (2,2048,4096)
  bf16* vt   = alloc(16777216);   // V^T per head     (16,512,2048)
  bf16* ctx  = alloc(67108864);   // attention out    (2,2048,16384)

  cvt_bf16<<<8192,  256, 0, stream>>>(x,   xb,  2097152);
  cvt_bf16<<<8192,  256, 0, stream>>>(WQw, wqb, 2097152);
  cvt_bf16<<<2048,  256, 0, stream>>>(WKw, wkb, 524288);
  cvt_bf16<<<8192,  256, 0, stream>>>(WVw, wvb, 2097152);
  cvt_bf16<<<32768, 256, 0, stream>>>(W0w, w0b, 8388608);

  gemm256<1><<<256, 512, 0, stream>>>(xb, wqb, qlin, WQb, 4096, 4096, 4096);
  gemm_bt<1><<<256, 256, 0, stream>>>(xb, wkb, klin, WKb, 4096, 1024, 4096);
  gemm256<1><<<256, 512, 0, stream>>>(xb, wvb, vlin, WVb, 4096, 4096, 4096);

  transpose_v<<<dim3(32, 8, 16), 256, 0, stream>>>(vlin, vt);

  attn<<<1024, 512, 0, stream>>>(qlin, klin, vt, ctx);

  gemm256<0><<<256, 512, 0, stream>>>(ctx, w0b, out, W0b, 4096, 4096, 16384);
}

// Round 13
// 1149.545 us; speedup vs baseline: 1.0068x; 1.0068x over previous
//
#include <hip/hip_runtime.h>
#include <stdint.h>

typedef __bf16 bf16;
typedef bf16 bf16x8 __attribute__((ext_vector_type(8)));
typedef float f32x4 __attribute__((ext_vector_type(4)));
typedef int int4v __attribute__((ext_vector_type(4)));
typedef uint32_t u32;

#define DEV static __device__ __forceinline__
#define SBAR() __builtin_amdgcn_s_barrier()
#define SCHED0() __builtin_amdgcn_sched_barrier(0)

DEV void g2l16(const void* g, void* l) {
  __builtin_amdgcn_global_load_lds((__attribute__((address_space(1))) void*)g,
                                   (__attribute__((address_space(3))) void*)l, 16, 0, 0);
}

DEV u32 pkbf16(float a, float b) {
  union { bf16 h[2]; u32 w; } u;
  u.h[0] = (bf16)a; u.h[1] = (bf16)b;
  return u.w;
}

DEV float fexp2(float x) { return __builtin_amdgcn_exp2f(x); }

// ---------------------------------------------------------------- cvt f32->bf16
__global__ void cvt_bf16(const float* __restrict__ in, bf16* __restrict__ out, int n8) {
  const int i = blockIdx.x * 256 + threadIdx.x;
  if (i >= n8) return;
  const f32x4* p = (const f32x4*)in + (size_t)i * 2;
  const f32x4 a = p[0], b = p[1];
  bf16x8 o;
  o[0]=(bf16)a[0]; o[1]=(bf16)a[1]; o[2]=(bf16)a[2]; o[3]=(bf16)a[3];
  o[4]=(bf16)b[0]; o[5]=(bf16)b[1]; o[6]=(bf16)b[2]; o[7]=(bf16)b[3];
  ((bf16x8*)out)[i] = o;
}

// ---------------------------------------------------------------- MFMA quadrant helper
template<int MO, int NO>
DEV void mmaq(f32x4 (&acc)[8][4], const bf16x8 (&af)[4][2], const bf16x8 (&bf)[2][2]) {
#pragma unroll
  for (int m2 = 0; m2 < 4; ++m2)
#pragma unroll
    for (int n2 = 0; n2 < 2; ++n2)
#pragma unroll
      for (int kk = 0; kk < 2; ++kk)
        acc[MO + m2][NO + n2] = __builtin_amdgcn_mfma_f32_16x16x32_bf16(
            af[m2][kk], bf[n2][kk], acc[MO + m2][NO + n2], 0, 0, 0);
}

// ---------------------------------------------------------------- GEMM 256x256
// Round-13: MINIMAL-BARRIER schedule. Rounds 11-12 proved the 8-phase
// RD->bar->MFMA->bar structure serializes LDS reads against MFMA (measured
// 8944 cyc/iter = 4966 MFMA + 3072 reads + overhead, MfmaUtil stuck ~52%).
// Only true hazards keep barriers:
//   BAR1 (after vmcnt(4)):  buf0(t) staged-data ready           [RAW]
//   BAR2: all waves read B-buf0 -> safe to re-stage B-buf0(t+2) [WAR]
//   BAR3: all waves read A-buf0 -> safe to re-stage A-buf0(t+2) [WAR]
//   BAR4 (after vmcnt(8)):  buf1(t+1) ready                     [RAW]
//   BAR5: all waves read B-buf1 -> safe to re-stage B-buf1(t+3) [WAR]
//   (A-buf1 WAR is covered by next iteration's BAR1.)
// Between barriers waves free-run {ds_read, MFMA} -> 2 waves/SIMD skew lets
// one wave's MFMA cover the other's reads. Every RD value is consumed by an
// MFMA before the next WAR barrier (loads can't sink past consumers);
// sched_barrier(0) pins register-only MFMAs at WAR barriers (guide rule #18).
// vmcnt audit (16 loads/iter, issue order A1,B0,A0,B1):
//   loop-top in-flight 12 = B0(t),A0(t),B1(t+1); vmcnt(4) drains B0,A0.
//   mid in-flight 16 = B1(t+1),A1(t+1),B0(t+2),A0(t+2); vmcnt(8) drains B1,A1.
template<int OUT_BF16>
__global__ __launch_bounds__(512, 2)
void gemm256(const bf16* __restrict__ A, const bf16* __restrict__ Bt,
             void* __restrict__ Cout, const float* __restrict__ bias,
             int M, int N, int K) {
  __shared__ __align__(16) char L[131072];
  const int tid = threadIdx.x, lane = tid & 63, wid = tid >> 6;
  const int wm = wid >> 2, wn = wid & 3;
  const int q = lane & 15, g = lane >> 4;
  const int mt = M >> 8;
  const int nwg = gridDim.x, bid = blockIdx.x;
  const int wg = (bid & 7) * (nwg >> 3) + (bid >> 3);   // XCD swizzle (nwg%8==0)
  const int bm = wg % mt, bn = wg / mt;
  const size_t Kb = (size_t)K * 2;
  const char* Ab = (const char*)A + (size_t)bm * 256 * Kb;
  const char* Bb = (const char*)Bt + (size_t)bn * 256 * Kb;
  const int NT = K >> 6;

  const int csw0 = (g ^ (q & 7)) << 4;
  const int csw1 = ((4 + g) ^ (q & 7)) << 4;
  const int baseA0 = wm * 16384 + q * 128;
  const int baseA1 = 65536 + baseA0;
  const int bBq = 32768 + (wn >> 1) * 16384 + (wn & 1) * 8192 + q * 128;
  const int baseB0 = bBq, baseB1 = 65536 + bBq;

#define RD_A(AF, BASE) do { _Pragma("unroll") \
  for (int m2_ = 0; m2_ < 4; ++m2_) { \
    (AF)[m2_][0] = *(const bf16x8*)(L + (BASE) + m2_ * 2048 + csw0); \
    (AF)[m2_][1] = *(const bf16x8*)(L + (BASE) + m2_ * 2048 + csw1); } } while (0)
#define RD_B(BF, BASE) do { _Pragma("unroll") \
  for (int n2_ = 0; n2_ < 2; ++n2_) { \
    (BF)[n2_][0] = *(const bf16x8*)(L + (BASE) + n2_ * 2048 + csw0); \
    (BF)[n2_][1] = *(const bf16x8*)(L + (BASE) + n2_ * 2048 + csw1); } } while (0)

  auto stage = [&](const char* gb, int ldsHalfBase, int halfRow, int tt) {
#pragma unroll
    for (int r2 = 0; r2 < 2; ++r2) {
      const int rel = r2 * 8192 + wid * 1024;
      const int o = rel + (lane << 4);
      const int row = o >> 7;
      const int kbyte = (o & 127) ^ ((row & 7) << 4);
      g2l16(gb + (size_t)(halfRow * 128 + row) * Kb + (size_t)(tt * 128 + kbyte),
            L + ldsHalfBase + rel);
    }
  };

  f32x4 acc[8][4];
  const f32x4 zero = {0.f, 0.f, 0.f, 0.f};
#pragma unroll
  for (int m = 0; m < 8; ++m)
#pragma unroll
    for (int n = 0; n < 4; ++n) acc[m][n] = zero;
  bf16x8 af[4][2], bflo[2][2], bfhi[2][2];

  // prologue: B0(0), A0(0), B1(1) = 12 loads/wave
  stage(Bb, 32768, 0, 0);          stage(Bb, 32768 + 16384, 1, 0);
  stage(Ab, 0, 0, 0);              stage(Ab, 16384, 1, 0);
  stage(Bb, 65536 + 32768, 0, 1);  stage(Bb, 65536 + 32768 + 16384, 1, 1);

  for (int t = 0; t < NT; t += 2) {
    const int tc1 = t + 1;
    const int tc2 = (t + 2 < NT) ? t + 2 : NT - 1;
    const int tc3 = (t + 3 < NT) ? t + 3 : NT - 1;
    // ======== tile t ========
    asm volatile("s_waitcnt vmcnt(4)" ::: "memory");
    SBAR();                                   // BAR1: buf0 ready (+A-buf1 WAR)
    RD_A(af, baseA0);
    RD_B(bflo, baseB0);
    RD_B(bfhi, baseB0 + 4096);
    stage(Ab, 65536, 0, tc1);  stage(Ab, 65536 + 16384, 1, tc1);
    __builtin_amdgcn_s_setprio(1);
    mmaq<0, 0>(acc, af, bflo);
    mmaq<0, 2>(acc, af, bfhi);
    __builtin_amdgcn_s_setprio(0);
    SCHED0();
    SBAR();                                   // BAR2: B-buf0 reads done
    RD_A(af, baseA0 + 8192);
    stage(Bb, 32768, 0, tc2);  stage(Bb, 32768 + 16384, 1, tc2);
    __builtin_amdgcn_s_setprio(1);
    mmaq<4, 0>(acc, af, bflo);
    mmaq<4, 2>(acc, af, bfhi);
    __builtin_amdgcn_s_setprio(0);
    SCHED0();
    SBAR();                                   // BAR3: A-buf0 reads done
    stage(Ab, 0, 0, tc2);  stage(Ab, 16384, 1, tc2);
    // ======== tile t+1 ========
    asm volatile("s_waitcnt vmcnt(8)" ::: "memory");
    SBAR();                                   // BAR4: buf1 ready
    RD_A(af, baseA1);
    RD_B(bflo, baseB1);
    RD_B(bfhi, baseB1 + 4096);
    __builtin_amdgcn_s_setprio(1);
    mmaq<0, 0>(acc, af, bflo);
    mmaq<0, 2>(acc, af, bfhi);
    __builtin_amdgcn_s_setprio(0);
    SCHED0();
    SBAR();                                   // BAR5: B-buf1 reads done
    RD_A(af, baseA1 + 8192);
    stage(Bb, 65536 + 32768, 0, tc3);  stage(Bb, 65536 + 32768 + 16384, 1, tc3);
    __builtin_amdgcn_s_setprio(1);
    mmaq<4, 0>(acc, af, bflo);
    mmaq<4, 2>(acc, af, bfhi);
    __builtin_amdgcn_s_setprio(0);
    SCHED0();
    // A-buf1 WAR fence = next iteration's BAR1 (stage A-buf1 issued after it)
  }
  asm volatile("s_waitcnt vmcnt(0)" ::: "memory");

  const int row0 = bm * 256 + wm * 128 + g * 4;
  const int col0 = bn * 256 + wn * 64 + q;
#pragma unroll
  for (int n = 0; n < 4; ++n) {
    const int col = col0 + n * 16;
    const float bv = bias[col];
#pragma unroll
    for (int m = 0; m < 8; ++m) {
#pragma unroll
      for (int r = 0; r < 4; ++r) {
        const int row = row0 + m * 16 + r;
        const float v = acc[m][n][r] + bv;
        if (OUT_BF16) ((bf16*)Cout)[(size_t)row * N + col] = (bf16)v;
        else          ((float*)Cout)[(size_t)row * N + col] = v;
      }
    }
  }
#undef RD_A
#undef RD_B
}

// ---------------------------------------------------------------- GEMM 128x128 (small N)
template<int OUT_BF16>
__global__ __launch_bounds__(256, 2)
void gemm_bt(const bf16* __restrict__ A, const bf16* __restrict__ Bt,
             void* __restrict__ Cout, const float* __restrict__ bias,
             int M, int N, int K) {
  __shared__ __align__(16) char As[16384];
  __shared__ __align__(16) char Bs[16384];
  const int tid  = threadIdx.x;
  const int lane = tid & 63;
  const int wid  = tid >> 6;
  const int mt = M >> 7;
  const int nwg = gridDim.x;
  const int bid = blockIdx.x;
  const int wg = (bid & 7) * (nwg >> 3) + (bid >> 3);
  const int bm = wg % mt;
  const int bn = wg / mt;

  const size_t Kb = (size_t)K * 2;
  const char* Ab = (const char*)A + (size_t)bm * 128 * Kb;
  const char* Bb = (const char*)Bt + (size_t)bn * 128 * Kb;

  const int wr = wid >> 1, wc = wid & 1;
  const int q = lane & 15, g = lane >> 4;

  const f32x4 zero = {0.f, 0.f, 0.f, 0.f};
  f32x4 acc[4][4];
#pragma unroll
  for (int m = 0; m < 4; ++m)
#pragma unroll
    for (int n = 0; n < 4; ++n) acc[m][n] = zero;

  for (int k0 = 0; k0 < K; k0 += 64) {
    __syncthreads();
#pragma unroll
    for (int it = 0; it < 4; ++it) {
      const int obase = (it * 4 + wid) << 10;
      const int o = obase + (lane << 4);
      const int row = o >> 7;
      const int kbyte = (o & 127) ^ ((row & 7) << 4);
      g2l16(Ab + (size_t)row * Kb + (size_t)(k0 * 2 + kbyte), As + obase);
      g2l16(Bb + (size_t)row * Kb + (size_t)(k0 * 2 + kbyte), Bs + obase);
    }
    __syncthreads();
#pragma unroll
    for (int kk = 0; kk < 2; ++kk) {
      bf16x8 af[4], bfv[4];
#pragma unroll
      for (int m = 0; m < 4; ++m) {
        const int r = wr * 64 + m * 16 + q;
        const int byte = (r * 128 + kk * 64 + g * 16) ^ ((r & 7) << 4);
        af[m] = *(const bf16x8*)(As + byte);
      }
#pragma unroll
      for (int n = 0; n < 4; ++n) {
        const int r = wc * 64 + n * 16 + q;
        const int byte = (r * 128 + kk * 64 + g * 16) ^ ((r & 7) << 4);
        bfv[n] = *(const bf16x8*)(Bs + byte);
      }
#pragma unroll
      for (int m = 0; m < 4; ++m)
#pragma unroll
        for (int n = 0; n < 4; ++n)
          acc[m][n] = __builtin_amdgcn_mfma_f32_16x16x32_bf16(af[m], bfv[n], acc[m][n], 0, 0, 0);
    }
  }

  const int col0 = bn * 128 + wc * 64 + q;
  const int row0 = bm * 128 + wr * 64 + g * 4;
#pragma unroll
  for (int n = 0; n < 4; ++n) {
    const int col = col0 + n * 16;
    const float bv = bias[col];
#pragma unroll
    for (int m = 0; m < 4; ++m) {
#pragma unroll
      for (int r = 0; r < 4; ++r) {
        const int row = row0 + m * 16 + r;
        const float v = acc[m][n][r] + bv;
        if (OUT_BF16) ((bf16*)Cout)[(size_t)row * N + col] = (bf16)v;
        else          ((float*)Cout)[(size_t)row * N + col] = v;
      }
    }
  }
}

// ---------------------------------------------------------------- V transpose per head
__global__ void transpose_v(const bf16* __restrict__ vlin, bf16* __restrict__ vt) {
  __shared__ __align__(16) bf16 t[64][80];
  const int tid = threadIdx.x;
  const int bh = blockIdx.z;
  const int jt = blockIdx.x, dt = blockIdx.y;
  const bf16* src = vlin + (size_t)bh * 1048576 + (size_t)(jt * 64) * 512 + dt * 64;
  bf16* dst = vt + (size_t)bh * 1048576 + (size_t)(dt * 64) * 2048 + jt * 64;
#pragma unroll
  for (int it = 0; it < 2; ++it) {
    const int c = it * 256 + tid;
    const int r = c >> 3, c8 = (c & 7) * 8;
    *(int4v*)&t[r][c8] = *(const int4v*)(src + (size_t)r * 512 + c8);
  }
  __syncthreads();
#pragma unroll
  for (int it = 0; it < 2; ++it) {
    const int c = it * 256 + tid;
    const int d = c >> 3, j8 = (c & 7) * 8;
    bf16x8 v;
#pragma unroll
    for (int jj = 0; jj < 8; ++jj) v[jj] = t[j8 + jj][d];
    *(bf16x8*)(dst + (size_t)d * 2048 + j8) = v;
  }
}

// ---------------------------------------------------------------- flash attention
// Q: [b][hq][2048][128], K: [b][h][2048][128], VT: [b][h][512][2048], O: [b][hq][2048][512]
// Spill-free dbuf via __syncthreads (VGPR 108 + 128 acc = 236 regs -> 1 block/CU,
// 2 waves/SIMD; register-bound). Global LPT dispatch: 1D grid, qt = 15 - (bid>>6).
// KEEP __syncthreads here: raw-asm sync variants spilled ~1GB scratch (rounds 6-8).
__global__ __launch_bounds__(512, 2)
void attn(const bf16* __restrict__ Q, const bf16* __restrict__ Kl,
          const bf16* __restrict__ VT, bf16* __restrict__ O) {
  constexpr float SC = 0.08838834764831845f * 1.4426950408889634f; // 1/sqrt(128)*log2(e)
  __shared__ __align__(16) char L[81920];   // buf bb in {0,40960}: K 8KB | V 32KB
  const int tid = threadIdx.x, lane = tid & 63, wid = tid >> 6;
  const int bid = blockIdx.x;
  const int qt = 15 - (bid >> 6);           // global LPT: longest first
  const int hq = (bid >> 1) & 31;
  const int b  = bid & 1;
  const int h = hq & 7;
  const char* qb = (const char*)(Q + (((size_t)b * 32 + hq) << 18));
  const char* kb = (const char*)(Kl + (((size_t)b * 8 + h) << 18));
  const char* vb = (const char*)(VT + (((size_t)b * 8 + h) << 20));
  bf16* ob = (bf16*)(O + (((size_t)b * 32 + hq) << 20));

  const int g = lane >> 4, q = lane & 15;
  const int qrow = qt * 128 + wid * 16 + q;
  const float NEGINF = -__builtin_inff();

  auto stageKV = [&](int j0, int bbase) {
    {   // K tile [32][128], XOR swizzled
      const int obase = wid << 10;
      const int o = obase + (lane << 4);
      const int row = o >> 8;
      const int cb = (o & 255) ^ ((row & 7) << 4);
      g2l16(kb + (size_t)(j0 + row) * 256 + cb, L + bbase + obase);
    }
#pragma unroll
    for (int it = 0; it < 4; ++it) {   // V tile [512][32], granule-permuted
      const int obase = (it * 8 + wid) << 10;
      const int o = obase + (lane << 4);
      const int sl = o >> 4;
      const int dpair = sl >> 3;
      const int w2 = (sl & 7) ^ (dpair & 7);
      const int d = dpair * 2 + (w2 >> 2);
      const int jo = w2 & 3;
      g2l16(vb + (size_t)d * 4096 + (size_t)(j0 + jo * 8) * 2,
            L + bbase + 8192 + obase);
    }
  };

  bf16x8 qf[4];
#pragma unroll
  for (int kk = 0; kk < 4; ++kk)
    qf[kk] = *(const bf16x8*)(qb + (size_t)qrow * 256 + kk * 64 + g * 16);

  const f32x4 zero = {0.f, 0.f, 0.f, 0.f};
  f32x4 acc[32];
#pragma unroll
  for (int i = 0; i < 32; ++i) acc[i] = zero;
  float mrun = NEGINF, lrun = 0.f;

  const int ntiles = qt * 4 + 4;
  const int jmax = (ntiles - 1) * 32;
  stageKV(0, 0);
  __syncthreads();          // drain tile 0
  int bb = 0;

#pragma unroll 1
  for (int jt = 0; jt < ntiles; ++jt) {
    const int j0 = jt * 32;
    const int jn = (j0 < jmax) ? j0 + 32 : jmax;   // clamp: harmless re-stage at end
    stageKV(jn, bb ^ 40960);   // in flight during this tile's compute
    const char* KsB = L + bb;
    const char* VsB = L + bb + 8192;

    // S^T = K * Q^T  (D: col = q, row = j = 4*g + r [+16])
    f32x4 s0 = zero, s1 = zero;
    __builtin_amdgcn_s_setprio(1);
#pragma unroll
    for (int kk = 0; kk < 4; ++kk) {
      {
        const int r = q;
        const int byte = (r * 256 + kk * 64 + g * 16) ^ ((r & 7) << 4);
        const bf16x8 kf = *(const bf16x8*)(KsB + byte);
        s0 = __builtin_amdgcn_mfma_f32_16x16x32_bf16(kf, qf[kk], s0, 0, 0, 0);
      }
      {
        const int r = 16 + q;
        const int byte = (r * 256 + kk * 64 + g * 16) ^ ((r & 7) << 4);
        const bf16x8 kf = *(const bf16x8*)(KsB + byte);
        s1 = __builtin_amdgcn_mfma_f32_16x16x32_bf16(kf, qf[kk], s1, 0, 0, 0);
      }
    }
    __builtin_amdgcn_s_setprio(0);

    float sv[8];
#pragma unroll
    for (int r = 0; r < 4; ++r) {
      float v0 = s0[r] * SC;
      float v1 = s1[r] * SC;
      if (j0 + g * 4 + r > qrow)      v0 = NEGINF;
      if (j0 + 16 + g * 4 + r > qrow) v1 = NEGINF;
      sv[r] = v0; sv[4 + r] = v1;
    }
    float pmax = fmaxf(fmaxf(fmaxf(sv[0], sv[1]), fmaxf(sv[2], sv[3])),
                       fmaxf(fmaxf(sv[4], sv[5]), fmaxf(sv[6], sv[7])));
    pmax = fmaxf(pmax, __shfl_xor(pmax, 16));
    pmax = fmaxf(pmax, __shfl_xor(pmax, 32));

    if (!__all(pmax <= mrun + 11.5f)) {     // defer-max rescale
      const float mnew = fmaxf(mrun, pmax);
      const float cf = fexp2(mrun - mnew);
      float cfr[4];
#pragma unroll
      for (int r = 0; r < 4; ++r) cfr[r] = __shfl(cf, g * 4 + r);
#pragma unroll
      for (int i = 0; i < 32; ++i) {
        acc[i][0] *= cfr[0]; acc[i][1] *= cfr[1];
        acc[i][2] *= cfr[2]; acc[i][3] *= cfr[3];
      }
      lrun *= cf;
      mrun = mnew;
    }

    u32 u0[2], u1[2];
    {
      const float p0 = fexp2(sv[0] - mrun), p1 = fexp2(sv[1] - mrun);
      const float p2 = fexp2(sv[2] - mrun), p3 = fexp2(sv[3] - mrun);
      const float p4 = fexp2(sv[4] - mrun), p5 = fexp2(sv[5] - mrun);
      const float p6 = fexp2(sv[6] - mrun), p7 = fexp2(sv[7] - mrun);
      lrun += ((p0 + p1) + (p2 + p3)) + ((p4 + p5) + (p6 + p7));
      u0[0] = pkbf16(p0, p1); u0[1] = pkbf16(p2, p3);
      u1[0] = pkbf16(p4, p5); u1[1] = pkbf16(p6, p7);
    }

    // Redistribute P^T into MFMA A-layout: lane needs j = 8g+2i, 8g+2i+1
    u32 aw[4];
#pragma unroll
    for (int i = 0; i < 4; ++i) {
      const int src = ((2 * g + (i >> 1)) & 3) * 16 + q;
      const u32 v0 = (u32)__shfl((int)u0[i & 1], src);
      const u32 v1 = (u32)__shfl((int)u1[i & 1], src);
      aw[i] = (g < 2) ? v0 : v1;
    }
    union { u32 w[4]; bf16x8 v; } pu;
    pu.w[0] = aw[0]; pu.w[1] = aw[1]; pu.w[2] = aw[2]; pu.w[3] = aw[3];
    const bf16x8 pa = pu.v;

    __builtin_amdgcn_s_setprio(1);
#pragma unroll
    for (int nd = 0; nd < 32; ++nd) {
      const int d = nd * 16 + q;
      const int w2 = ((d & 1) * 4 + g) ^ ((d >> 1) & 7);
      const int byte = (d >> 1) * 128 + w2 * 16;
      const bf16x8 vf = *(const bf16x8*)(VsB + byte);
      acc[nd] = __builtin_amdgcn_mfma_f32_16x16x32_bf16(pa, vf, acc[nd], 0, 0, 0);
    }
    __builtin_amdgcn_s_setprio(0);
    __syncthreads();   // drains next-tile stage (overlapped with compute above)
    bb ^= 40960;       // and fences all reads of buf bb before it is overwritten
  }

  float lt = lrun + __shfl_xor(lrun, 16);
  lt += __shfl_xor(lt, 32);
  const float linv = 1.f / lt;
  float lr[4];
#pragma unroll
  for (int r = 0; r < 4; ++r) lr[r] = __shfl(linv, g * 4 + r);
#pragma unroll
  for (int nd = 0; nd < 32; ++nd) {
#pragma unroll
    for (int r = 0; r < 4; ++r) {
      const int qq = qt * 128 + wid * 16 + g * 4 + r;
      ob[(size_t)qq * 512 + nd * 16 + q] = (bf16)(acc[nd][r] * lr[r]);
    }
  }
}

// ---------------------------------------------------------------- launch
extern "C" void kernel_launch(void* const* d_in, const int* in_sizes, int n_in,
                              void* d_out, int out_size, void* d_ws, size_t ws_size,
                              hipStream_t stream) {
  (void)in_sizes; (void)n_in; (void)out_size; (void)ws_size;
  const float* x   = (const float*)d_in[0];
  const float* WQw = (const float*)d_in[2];
  const float* WQb = (const float*)d_in[3];
  const float* WKw = (const float*)d_in[4];
  const float* WKb = (const float*)d_in[5];
  const float* WVw = (const float*)d_in[6];
  const float* WVb = (const float*)d_in[7];
  const float* W0w = (const float*)d_in[8];
  const float* W0b = (const float*)d_in[9];
  float* out = (float*)d_out;

  bf16* ws = (bf16*)d_ws;
  size_t off = 0;
  auto alloc = [&](size_t n) { bf16* p = ws + off; off += n; return p; };
  bf16* xb   = alloc(16777216);   // x bf16           (2,2048,4096)
  bf16* wqb  = alloc(16777216);   // WQ bf16          (4096,4096)
  bf16* wkb  = alloc(4194304);    // WK bf16          (1024,4096)
  bf16* wvb  = alloc(16777216);   // WV bf16          (4096,4096)
  bf16* w0b  = alloc(67108864);   // W0 bf16          (4096,16384)
  bf16* qlin = alloc(16777216);   // Q                (2,2048,4096)
  bf16* klin = alloc(4194304);    // K                (2,2048,1024)
  bf16* vlin = alloc(16777216);   // V                (2,2048,4096)
  bf16* vt   = alloc(16777216);   // V^T per head     (16,512,2048)
  bf16* ctx  = alloc(67108864);   // attention out    (2,2048,16384)

  cvt_bf16<<<8192,  256, 0, stream>>>(x,   xb,  2097152);
  cvt_bf16<<<8192,  256, 0, stream>>>(WQw, wqb, 2097152);
  cvt_bf16<<<2048,  256, 0, stream>>>(WKw, wkb, 524288);
  cvt_bf16<<<8192,  256, 0, stream>>>(WVw, wvb, 2097152);
  cvt_bf16<<<32768, 256, 0, stream>>>(W0w, w0b, 8388608);

  gemm256<1><<<256, 512, 0, stream>>>(xb, wqb, qlin, WQb, 4096, 4096, 4096);
  gemm_bt<1><<<256, 256, 0, stream>>>(xb, wkb, klin, WKb, 4096, 1024, 4096);
  gemm256<1><<<256, 512, 0, stream>>>(xb, wvb, vlin, WVb, 4096, 4096, 4096);

  transpose_v<<<dim3(32, 8, 16), 256, 0, stream>>>(vlin, vt);

  attn<<<1024, 512, 0, stream>>>(qlin, klin, vt, ctx);

  gemm256<0><<<256, 512, 0, stream>>>(ctx, w0b, out, W0b, 4096, 4096, 16384);
}